// Round 1
// baseline (872.972 us; speedup 1.0000x reference)
//
#include <hip/hip_runtime.h>
#include <hip/hip_bf16.h>

#define B_TOTAL 131072

typedef __attribute__((ext_vector_type(8))) short short8;   // 8 bf16 (4 VGPRs) MFMA A/B frag
typedef __attribute__((ext_vector_type(4))) short short4v;  // 8B load
typedef __attribute__((ext_vector_type(4))) float f32x4;    // MFMA C/D frag
typedef unsigned int uint;

__device__ __forceinline__ short f2bf(float f) {
  union { float f; uint u; } x; x.f = f;
  uint r = x.u + 0x7fffu + ((x.u >> 16) & 1u);  // RTNE
  return (short)(r >> 16);
}
__device__ __forceinline__ float bf2f(short b) {
  union { float f; uint u; } x; x.u = ((uint)(unsigned short)b) << 16;
  return x.f;
}

__device__ __forceinline__ void gl_lds16(const void* g, void* l) {
  __builtin_amdgcn_global_load_lds((const __attribute__((address_space(1))) uint*)g,
                                   (__attribute__((address_space(3))) uint*)l, 16, 0, 0);
}

// ---------------- weight convert + transpose: w[K][N] f32 -> wt[N][Kpad] bf16 (zero pad) ----
__global__ void conv_wT(const float* __restrict__ w, short* __restrict__ wt,
                        int K, int N, int Kpad) {
  const int i = blockIdx.x * 256 + threadIdx.x;
  if (i >= N * Kpad) return;
  const int n = i / Kpad;
  const int k = i % Kpad;
  wt[(long)n * Kpad + k] = (k < K) ? f2bf(w[(long)k * N + n]) : (short)0;
}

// ---------------- enc kernel: builds enc[M][576] bf16 (pad zeros) and t[M][256] bf16 --------
__global__ __launch_bounds__(256)
void enc_k(const float* __restrict__ state, const float* __restrict__ action,
           const float* __restrict__ sensors, const float* __restrict__ tw1,
           const float* __restrict__ tb1, short* __restrict__ enc,
           short* __restrict__ tbuf, int M) {
  __shared__ float sval[64][17];
  __shared__ float wexp[64][32];
  __shared__ float sens[96];
  const int tid = threadIdx.x;
  const int rb = blockIdx.x * 64;
  if (tid < 96) sens[tid] = sensors[tid];
  for (int i = tid; i < 64 * 17; i += 256) {
    const int r = i / 17, c = i % 17;
    const long grow = rb + r;
    sval[r][c] = (c < 13) ? state[grow * 13 + c] : action[grow * 4 + (c - 13)];
  }
  __syncthreads();
  for (int i = tid; i < 64 * 32; i += 256) {
    const int r = i >> 5, s = i & 31;
    const float dx = sens[s*3+0] - sval[r][0];
    const float dy = sens[s*3+1] - sval[r][1];
    const float dz = sens[s*3+2] - sval[r][2];
    const float d = sqrtf(dx*dx + dy*dy + dz*dz);
    wexp[r][s] = __expf(-2.0f * d);   // exp(-dist/0.5)
  }
  __syncthreads();
  // enc rows: 544 real elems (s*17+c), padded to 576
  for (int i = tid; i < 64 * 72; i += 256) {
    const int r = i / 72, c8 = i % 72;
    short8 v;
#pragma unroll
    for (int j = 0; j < 8; ++j) {
      const int k = c8 * 8 + j;
      float f = 0.f;
      if (k < 544) { const int s = k / 17, c = k % 17; f = sval[r][c] * wexp[r][s]; }
      v[j] = f2bf(f);
    }
    *(short8*)&enc[((long)(rb + r)) * 576 + c8 * 8] = v;
  }
  // t = tanh(pos @ tw1 + tb1), tw1 is [3][256]
  for (int i = tid; i < 64 * 256; i += 256) {
    const int r = i >> 8, j = i & 255;
    const float v = tanhf(sval[r][0] * tw1[j] + sval[r][1] * tw1[256 + j] +
                          sval[r][2] * tw1[512 + j] + tb1[j]);
    tbuf[((long)(rb + r)) * 256 + j] = f2bf(v);
  }
}

// ---------------- GEMM: C[M][N] = act(A[M][LDA(bf16)] @ Bt[N][K]^T + bias) -----------------
// 128x128 tile, 4 waves (64x64 each), BK=64, double-buffered LDS, global_load_lds width 16,
// row&7 XOR swizzle applied on BOTH the stage source chunk and the ds_read (guideline 21).
// ACT: 0 none, 1 relu, 2 tanh.
template<int N, int K, int LDA, int ACT>
__global__ __launch_bounds__(256, 2)
void gemm_bt(const short* __restrict__ A, const short* __restrict__ Bt,
             const float* __restrict__ bias, short* __restrict__ C) {
  constexpr int NT = K / 64;
  constexpr int NTN = N / 128;
  __shared__ __align__(16) short As[2][128 * 64];
  __shared__ __align__(16) short Bs[2][128 * 64];
  const int tid = threadIdx.x;
  const int wave = tid >> 6;
  const int lane = tid & 63;
  const int tm = blockIdx.x / NTN;
  const int tn = blockIdx.x % NTN;
  const long arow0 = (long)tm * 128;
  const long brow0 = (long)tn * 128;

  auto stage = [&](int b, int kt) {
    const int k0 = kt * 64;
#pragma unroll
    for (int it = 0; it < 4; ++it) {
      const int cw = it * 4 + wave;        // 16 wave-calls of 1KB each
      const int ch = cw * 64 + lane;       // chunk id (16B) 0..1023
      const int row = ch >> 3;
      const int cs = (ch & 7) ^ (row & 7); // inverse-swizzled source chunk
      gl_lds16(A + (arow0 + row) * (long)LDA + (k0 + cs * 8), &As[b][cw * 512]);
      gl_lds16(Bt + (brow0 + row) * (long)K + (k0 + cs * 8), &Bs[b][cw * 512]);
    }
  };

  const int wr = (wave >> 1) * 64;
  const int wc = (wave & 1) * 64;
  const int fr = lane & 15;
  const int fg = lane >> 4;

  f32x4 acc[4][4] = {};

  stage(0, 0);
  for (int kt = 0; kt < NT; ++kt) {
    const int cur = kt & 1;
    __syncthreads();
    if (kt + 1 < NT) stage(cur ^ 1, kt + 1);
    const short* Ab = As[cur];
    const short* Bb = Bs[cur];
    short8 af[4][2], bfr[4][2];
#pragma unroll
    for (int m = 0; m < 4; ++m)
#pragma unroll
      for (int kk = 0; kk < 2; ++kk) {
        const int row = wr + m * 16 + fr;
        const int c = kk * 4 + fg;
        af[m][kk] = *(const short8*)&Ab[row * 64 + ((c ^ (row & 7)) * 8)];
      }
#pragma unroll
    for (int n = 0; n < 4; ++n)
#pragma unroll
      for (int kk = 0; kk < 2; ++kk) {
        const int col = wc + n * 16 + fr;
        const int c = kk * 4 + fg;
        bfr[n][kk] = *(const short8*)&Bb[col * 64 + ((c ^ (col & 7)) * 8)];
      }
#pragma unroll
    for (int kk = 0; kk < 2; ++kk)
#pragma unroll
      for (int m = 0; m < 4; ++m)
#pragma unroll
        for (int n = 0; n < 4; ++n)
          acc[m][n] = __builtin_amdgcn_mfma_f32_16x16x32_bf16(af[m][kk], bfr[n][kk],
                                                              acc[m][n], 0, 0, 0);
  }

  float bv[4];
#pragma unroll
  for (int n = 0; n < 4; ++n) bv[n] = bias[tn * 128 + wc + n * 16 + fr];
#pragma unroll
  for (int m = 0; m < 4; ++m)
#pragma unroll
    for (int n = 0; n < 4; ++n) {
      const long col = brow0 + wc + n * 16 + fr;
#pragma unroll
      for (int r = 0; r < 4; ++r) {
        const long row = arow0 + wr + m * 16 + fg * 4 + r;  // m89-verified C/D layout
        float v = acc[m][n][r] + bv[n];
        if (ACT == 1) v = fmaxf(v, 0.f);
        else if (ACT == 2) v = tanhf(v);
        C[row * (long)N + col] = f2bf(v);
      }
    }
}

// ---------------- final: interaction -> 13, + bias net, residual, quat normalize -----------
__global__ __launch_bounds__(256)
void final_k(const short* __restrict__ branch, const short* __restrict__ trunk,
             const float* __restrict__ state, const float* __restrict__ pw,
             const float* __restrict__ pbias, const float* __restrict__ qw1,
             const float* __restrict__ qb1, const float* __restrict__ qw2,
             const float* __restrict__ qb2, const float* __restrict__ rwp,
             float* __restrict__ out, int M) {
  const int lane = threadIdx.x & 63;
  const int wid = (blockIdx.x * blockDim.x + threadIdx.x) >> 6;
  const int nw = (gridDim.x * blockDim.x) >> 6;
  float pwr[4][13];
#pragma unroll
  for (int j = 0; j < 4; ++j)
#pragma unroll
    for (int c = 0; c < 13; ++c) pwr[j][c] = pw[(lane * 4 + j) * 13 + c];
  float qw1r[2][3], qb1r[2], qw2r[2][13];
#pragma unroll
  for (int h = 0; h < 2; ++h) {
    const int j = lane + h * 64;
    qw1r[h][0] = qw1[j]; qw1r[h][1] = qw1[128 + j]; qw1r[h][2] = qw1[256 + j];
    qb1r[h] = qb1[j];
#pragma unroll
    for (int c = 0; c < 13; ++c) qw2r[h][c] = qw2[j * 13 + c];
  }
  const float rw = rwp[0];
  const float pbq = (lane < 13) ? (pbias[lane] + qb2[lane]) : 0.f;

  for (long row = wid; row < M; row += nw) {
    const short4v bv = *(const short4v*)&branch[row * 256 + lane * 4];
    const short4v tv = *(const short4v*)&trunk[row * 256 + lane * 4];
    float part[13];
#pragma unroll
    for (int c = 0; c < 13; ++c) part[c] = 0.f;
#pragma unroll
    for (int j = 0; j < 4; ++j) {
      const float inter = bf2f(bv[j]) * bf2f(tv[j]);
#pragma unroll
      for (int c = 0; c < 13; ++c) part[c] += inter * pwr[j][c];
    }
    const float p0 = state[row * 13 + 0], p1 = state[row * 13 + 1], p2 = state[row * 13 + 2];
#pragma unroll
    for (int h = 0; h < 2; ++h) {
      const float hq = fmaxf(p0 * qw1r[h][0] + p1 * qw1r[h][1] + p2 * qw1r[h][2] + qb1r[h], 0.f);
#pragma unroll
      for (int c = 0; c < 13; ++c) part[c] += hq * qw2r[h][c];
    }
#pragma unroll
    for (int c = 0; c < 13; ++c) {
      float v = part[c];
      v += __shfl_xor(v, 32, 64);
      v += __shfl_xor(v, 16, 64);
      v += __shfl_xor(v, 8, 64);
      v += __shfl_xor(v, 4, 64);
      v += __shfl_xor(v, 2, 64);
      v += __shfl_xor(v, 1, 64);
      part[c] = v;
    }
    float dsel = 0.f;
#pragma unroll
    for (int c = 0; c < 13; ++c) if (lane == c) dsel = part[c];
    const float sv = (lane < 13) ? state[row * 13 + lane] : 0.f;
    float ns = sv + rw * (dsel + pbq);
    const float q0 = __shfl(ns, 3, 64), q1 = __shfl(ns, 4, 64);
    const float q2 = __shfl(ns, 5, 64), q3 = __shfl(ns, 6, 64);
    const float qn = sqrtf(q0 * q0 + q1 * q1 + q2 * q2 + q3 * q3) + 1e-8f;
    if (lane >= 3 && lane < 7) ns /= qn;
    if (lane < 13) out[row * 13 + lane] = ns;
  }
}

extern "C" void kernel_launch(void* const* d_in, const int* in_sizes, int n_in,
                              void* d_out, int out_size, void* d_ws, size_t ws_size,
                              hipStream_t stream) {
  const float* state  = (const float*)d_in[0];
  const float* action = (const float*)d_in[1];
  const float* sensors= (const float*)d_in[2];
  const float* bw1 = (const float*)d_in[3];
  const float* bb1 = (const float*)d_in[4];
  const float* bw2 = (const float*)d_in[5];
  const float* bb2 = (const float*)d_in[6];
  const float* bw3 = (const float*)d_in[7];
  const float* bb3 = (const float*)d_in[8];
  const float* tw1 = (const float*)d_in[9];
  const float* tb1 = (const float*)d_in[10];
  const float* tw2 = (const float*)d_in[11];
  const float* tb2 = (const float*)d_in[12];
  const float* qw1 = (const float*)d_in[13];
  const float* qb1 = (const float*)d_in[14];
  const float* qw2 = (const float*)d_in[15];
  const float* qb2 = (const float*)d_in[16];
  const float* pw  = (const float*)d_in[17];
  const float* pb  = (const float*)d_in[18];
  const float* rw  = (const float*)d_in[19];
  float* out = (float*)d_out;

  char* p = (char*)d_ws;
  short* wT1 = (short*)p; p += (size_t)1024 * 576 * 2;
  short* wT2 = (short*)p; p += (size_t)512 * 1024 * 2;
  short* wT3 = (short*)p; p += (size_t)256 * 512 * 2;
  short* wT4 = (short*)p; p += (size_t)256 * 256 * 2;
  const size_t fixed = (size_t)(p - (char*)d_ws);

  // per-row scratch: enc/h2 region (576) + h1 (1024) + t/branch (256) + trunk (256), bf16
  const size_t perrow = (576 + 1024 + 256 + 256) * 2;
  const size_t avail = (ws_size > fixed) ? ws_size - fixed : 0;
  long Mc = (long)(avail / perrow) & ~127L;
  if (Mc > B_TOTAL) Mc = B_TOTAL;
  if (Mc < 128) return;  // insufficient workspace

  conv_wT<<<dim3((1024 * 576 + 255) / 256), dim3(256), 0, stream>>>(bw1, wT1, 544, 1024, 576);
  conv_wT<<<dim3((512 * 1024 + 255) / 256), dim3(256), 0, stream>>>(bw2, wT2, 1024, 512, 1024);
  conv_wT<<<dim3((256 * 512 + 255) / 256), dim3(256), 0, stream>>>(bw3, wT3, 512, 256, 512);
  conv_wT<<<dim3((256 * 256 + 255) / 256), dim3(256), 0, stream>>>(tw2, wT4, 256, 256, 256);

  for (long row0 = 0; row0 < B_TOTAL; row0 += Mc) {
    long Mr = B_TOTAL - row0; if (Mr > Mc) Mr = Mc;
    char* q = p;
    short* encb = (short*)q; q += (size_t)Mc * 576 * 2;   // later reused as h2
    short* h1b  = (short*)q; q += (size_t)Mc * 1024 * 2;
    short* tb_  = (short*)q; q += (size_t)Mc * 256 * 2;   // t, later reused as branch
    short* trk  = (short*)q; q += (size_t)Mc * 256 * 2;
    short* h2b = encb;
    short* brb = tb_;

    enc_k<<<dim3(Mr / 64), dim3(256), 0, stream>>>(state + row0 * 13, action + row0 * 4,
                                                   sensors, tw1, tb1, encb, tb_, (int)Mr);
    gemm_bt<256, 256, 256, 2><<<dim3((Mr / 128) * 2), dim3(256), 0, stream>>>(tb_, wT4, tb2, trk);
    gemm_bt<1024, 576, 576, 1><<<dim3((Mr / 128) * 8), dim3(256), 0, stream>>>(encb, wT1, bb1, h1b);
    gemm_bt<512, 1024, 1024, 1><<<dim3((Mr / 128) * 4), dim3(256), 0, stream>>>(h1b, wT2, bb2, h2b);
    gemm_bt<256, 512, 512, 0><<<dim3((Mr / 128) * 2), dim3(256), 0, stream>>>(h2b, wT3, bb3, brb);
    final_k<<<dim3(512), dim3(256), 0, stream>>>(brb, trk, state + row0 * 13, pw, pb,
                                                 qw1, qb1, qw2, qb2, rw,
                                                 out + row0 * 13, (int)Mr);
  }
}

// Round 2
// 678.901 us; speedup vs baseline: 1.2859x; 1.2859x over previous
//
#include <hip/hip_runtime.h>
#include <hip/hip_bf16.h>

#define B_TOTAL 131072

typedef __attribute__((ext_vector_type(8))) short short8;   // 8 bf16 MFMA A/B frag
typedef __attribute__((ext_vector_type(4))) float f32x4;    // MFMA C/D frag
typedef unsigned int uint;

#define MFMA(a,b,c) __builtin_amdgcn_mfma_f32_16x16x32_bf16(a,b,c,0,0,0)

__device__ __forceinline__ short f2bf(float f) {
  union { float f; uint u; } x; x.f = f;
  uint r = x.u + 0x7fffu + ((x.u >> 16) & 1u);  // RTNE
  return (short)(r >> 16);
}

__device__ __forceinline__ void gl_lds16(const void* g, void* l) {
  __builtin_amdgcn_global_load_lds((const __attribute__((address_space(1))) uint*)g,
                                   (__attribute__((address_space(3))) uint*)l, 16, 0, 0);
}
// 16B-chunk swizzles (writer & reader use the same involution)
__device__ __forceinline__ int swz4(int c, int r) { return (c & ~3) | ((c ^ r ^ (r >> 2)) & 3); }
__device__ __forceinline__ int swz8(int c, int r) { return (c & ~7) | ((c ^ r) & 7); }

// ---- weight convert+transpose: w[K][N] f32 -> wt[N][Kpad] bf16 (zero pad) ----
__global__ void conv_wT(const float* __restrict__ w, short* __restrict__ wt,
                        int K, int N, int Kpad) {
  const int i = blockIdx.x * 256 + threadIdx.x;
  if (i >= N * Kpad) return;
  const int n = i / Kpad, k = i % Kpad;
  wt[(long)n * Kpad + k] = (k < K) ? f2bf(w[(long)k * N + n]) : (short)0;
}

// ---- small weights: pwT[16][256], qw1T[128][32], qw2T[16][128] (zero-padded) ----
__global__ void conv_small(const float* __restrict__ pw, const float* __restrict__ qw1,
                           const float* __restrict__ qw2, short* __restrict__ pwT,
                           short* __restrict__ qw1T, short* __restrict__ qw2T) {
  int t = blockIdx.x * 256 + threadIdx.x;
  if (t < 4096) { int c = t >> 8, k = t & 255; pwT[t] = (c < 13) ? f2bf(pw[k * 13 + c]) : (short)0; }
  else if (t < 8192) { int i = t - 4096; int j = i >> 5, k = i & 31;
    qw1T[i] = (k < 3) ? f2bf(qw1[k * 128 + j]) : (short)0; }
  else if (t < 10240) { int i = t - 8192; int c = i >> 7, j = i & 127;
    qw2T[i] = (c < 13) ? f2bf(qw2[j * 13 + c]) : (short)0; }
}

// ============ K1: enc (on the fly) -> h1 (chunked in regs) -> h2 ============
// 64 rows/block, 8 waves. enc[64][576] bf16 resident in LDS; h1 in 8 chunks of
// 128 cols: gemm1 (K=576, BK=96) -> relu -> LDS -> gemm2 accum (K=128, BK=32)
// into persistent h2 acc (64x512 per block).
__global__ __launch_bounds__(512)
void k1(const float* __restrict__ state, const float* __restrict__ action,
        const float* __restrict__ sensors,
        const short* __restrict__ w1T, const float* __restrict__ bb1,
        const short* __restrict__ w2T, const float* __restrict__ bb2,
        short* __restrict__ h2out) {
  __shared__ __align__(16) char lds[155648];
  short* encS = (short*)lds;                    // [64][72ch] swz8  (73728 B)
  char*  bReg = lds + 73728;                    // B1 dbuf 2x24576 / B2 dbuf 2x32768
  short* h1cS = (short*)(lds + 73728 + 65536);  // [64][128] swz8 (16384 B)
  float* svS  = (float*)h1cS;                   // [64*17] during enc build only
  float* wxS  = svS + 64 * 17;                  // [64*32]

  const int tid = threadIdx.x;
  const int wave = tid >> 6, lane = tid & 63;
  const int fr = lane & 15, fg = lane >> 4;
  const long rb = (long)blockIdx.x * 64;

  // ---- enc build ----
  for (int i = tid; i < 64 * 17; i += 512) {
    int r = i / 17, c = i % 17;
    svS[i] = (c < 13) ? state[(rb + r) * 13 + c] : action[(rb + r) * 4 + (c - 13)];
  }
  __syncthreads();
  for (int i = tid; i < 64 * 32; i += 512) {
    int r = i >> 5, s = i & 31;
    float dx = sensors[s * 3 + 0] - svS[r * 17 + 0];
    float dy = sensors[s * 3 + 1] - svS[r * 17 + 1];
    float dz = sensors[s * 3 + 2] - svS[r * 17 + 2];
    wxS[i] = __expf(-2.f * sqrtf(dx * dx + dy * dy + dz * dz));
  }
  __syncthreads();
  for (int i = tid; i < 64 * 72; i += 512) {
    int r = i / 72, c8 = i % 72;
    short8 v;
#pragma unroll
    for (int j = 0; j < 8; ++j) {
      int k = c8 * 8 + j;
      float f = 0.f;
      if (k < 544) { int s = k / 17, c = k % 17; f = svS[r * 17 + c] * wxS[r * 32 + s]; }
      v[j] = f2bf(f);
    }
    *(short8*)&encS[(r * 72 + swz8(c8, r)) * 8] = v;
  }

  const int wr1 = (wave >> 2) * 32, wc1 = (wave & 3) * 32;    // h1c [64][128] tile
  const int wrH = (wave >> 2) * 32, wcH = (wave & 3) * 128;   // h2  [64][512] tile

  f32x4 acc2[2][8] = {};

  for (int ch = 0; ch < 8; ++ch) {
    __syncthreads();  // prev-phase B/h1c reads done (and enc build on ch==0)
    // --- gemm1: h1c = relu(enc @ w1T[ch*128 ..][:]) ---
    auto stageB1 = [&](int buf, int ks) {
      char* dst = bReg + buf * 24576;
      const short* src0 = w1T + (long)(ch * 128) * 576 + ks * 96;
#pragma unroll
      for (int it = 0; it < 3; ++it) {
        int cw = it * 8 + wave;
        int chk = cw * 64 + lane;
        int rowB = chk / 12, c = chk % 12;
        gl_lds16(src0 + (long)rowB * 576 + swz4(c, rowB) * 8, dst + cw * 1024);
      }
    };
    f32x4 acc1[2][2] = {};
    stageB1(0, 0);
#pragma unroll
    for (int ks = 0; ks < 6; ++ks) {
      __syncthreads();
      if (ks < 5) stageB1((ks & 1) ^ 1, ks + 1);
      const short* Bb = (const short*)(bReg + (ks & 1) * 24576);
      short8 aF[2][3], bF[2][3];
#pragma unroll
      for (int mf = 0; mf < 2; ++mf)
#pragma unroll
        for (int kk = 0; kk < 3; ++kk) {
          int row = wr1 + mf * 16 + fr;
          int c8 = ks * 12 + kk * 4 + fg;
          aF[mf][kk] = *(const short8*)&encS[(row * 72 + swz8(c8, row)) * 8];
        }
#pragma unroll
      for (int nf = 0; nf < 2; ++nf)
#pragma unroll
        for (int kk = 0; kk < 3; ++kk) {
          int col = wc1 + nf * 16 + fr;
          int c = kk * 4 + fg;
          bF[nf][kk] = *(const short8*)&Bb[col * 96 + swz4(c, col) * 8];
        }
#pragma unroll
      for (int kk = 0; kk < 3; ++kk)
#pragma unroll
        for (int mf = 0; mf < 2; ++mf)
#pragma unroll
          for (int nf = 0; nf < 2; ++nf)
            acc1[mf][nf] = MFMA(aF[mf][kk], bF[nf][kk], acc1[mf][nf]);
    }
    // h1c epilogue: relu + bias -> LDS (swizzled); own-tile writes, no race
#pragma unroll
    for (int nf = 0; nf < 2; ++nf) {
      int col = wc1 + nf * 16 + fr;
      float bv = bb1[ch * 128 + col];
#pragma unroll
      for (int mf = 0; mf < 2; ++mf)
#pragma unroll
        for (int i = 0; i < 4; ++i) {
          int row = wr1 + mf * 16 + fg * 4 + i;
          float v = fmaxf(acc1[mf][nf][i] + bv, 0.f);
          h1cS[row * 128 + swz8(col >> 3, row) * 8 + (col & 7)] = f2bf(v);
        }
    }
    __syncthreads();  // h1c visible; B1 reads done -> B region reusable
    // --- gemm2: acc2 += h1c @ w2T[:, ch*128..] ---
    auto stageB2 = [&](int buf, int ks2) {
      char* dst = bReg + buf * 32768;
      const short* src0 = w2T + ch * 128 + ks2 * 32;
#pragma unroll
      for (int it = 0; it < 4; ++it) {
        int cw = it * 8 + wave;
        int chk = cw * 64 + lane;
        int rowB = chk >> 2, c = chk & 3;
        gl_lds16(src0 + (long)rowB * 1024 + swz4(c, rowB) * 8, dst + cw * 1024);
      }
    };
    stageB2(0, 0);
#pragma unroll
    for (int ks2 = 0; ks2 < 4; ++ks2) {
      __syncthreads();
      if (ks2 < 3) stageB2((ks2 & 1) ^ 1, ks2 + 1);
      const short* Bb = (const short*)(bReg + (ks2 & 1) * 32768);
      short8 aF[2], bF[8];
#pragma unroll
      for (int mf = 0; mf < 2; ++mf) {
        int row = wrH + mf * 16 + fr;
        aF[mf] = *(const short8*)&h1cS[row * 128 + swz8(ks2 * 4 + fg, row) * 8];
      }
#pragma unroll
      for (int nf = 0; nf < 8; ++nf) {
        int col = wcH + nf * 16 + fr;
        bF[nf] = *(const short8*)&Bb[col * 32 + swz4(fg, col) * 8];
      }
#pragma unroll
      for (int mf = 0; mf < 2; ++mf)
#pragma unroll
        for (int nf = 0; nf < 8; ++nf)
          acc2[mf][nf] = MFMA(aF[mf], bF[nf], acc2[mf][nf]);
    }
  }
  // ---- h2 write: relu(acc2 + bb2) ----
#pragma unroll
  for (int nf = 0; nf < 8; ++nf) {
    int col = wcH + nf * 16 + fr;
    float bv = bb2[col];
#pragma unroll
    for (int mf = 0; mf < 2; ++mf)
#pragma unroll
      for (int i = 0; i < 4; ++i) {
        long row = rb + wrH + mf * 16 + fg * 4 + i;
        h2out[row * 512 + col] = f2bf(fmaxf(acc2[mf][nf][i] + bv, 0.f));
      }
  }
}

// ============ K2: branch(h2@w3T) * trunk(tanh chain) -> 13-dim out ============
// 128 rows/block, 8 waves. t built on the fly; branch & trunk in regs;
// interaction -> LDS; pw-proj + bias-net via small MFMAs; residual + quat.
__global__ __launch_bounds__(512)
void k2(const short* __restrict__ h2, const float* __restrict__ state,
        const float* __restrict__ tw1, const float* __restrict__ tb1,
        const short* __restrict__ w3T, const float* __restrict__ bb3,
        const short* __restrict__ w4T, const float* __restrict__ tb2,
        const short* __restrict__ pwT, const short* __restrict__ qw1T,
        const short* __restrict__ qw2T, const float* __restrict__ qb1,
        const float* __restrict__ pb, const float* __restrict__ qb2,
        const float* __restrict__ rwp, float* __restrict__ out) {
  __shared__ __align__(16) char lds[135168];
  char* aReg = lds;                      // A dbuf 2x8192; later posPad(8192)+qw1T(8192)
  char* bReg = lds + 16384;              // B dbuf 2x16384; later hq[128][128]
  short* tS  = (short*)(lds + 49152);    // [128][256] swz8; later inter
  short* pwS = (short*)(lds + 114688);   // [16][256] swz8
  short* q2S = (short*)(lds + 122880);   // [16][128] swz8
  float* prS = (float*)(lds + 126976);   // [128][16] f32

  const int tid = threadIdx.x, wave = tid >> 6, lane = tid & 63;
  const int fr = lane & 15, fg = lane >> 4;
  const long rb = (long)blockIdx.x * 128;

  // stage pwT / qw2T once
  {
    int chk = wave * 64 + lane;
    { int row = chk >> 5, c = chk & 31;
      gl_lds16(pwT + (long)row * 256 + swz8(c, row) * 8, (char*)pwS + wave * 1024); }
    if (wave < 4) { int row = chk >> 4, c = chk & 15;
      gl_lds16(qw2T + (long)row * 128 + swz8(c, row) * 8, (char*)q2S + wave * 1024); }
  }
  // build t = tanh(pos @ tw1 + tb1) -> LDS
  for (int i = tid; i < 128 * 32; i += 512) {
    int r = i >> 5, c8 = i & 31;
    float p0 = state[(rb + r) * 13 + 0], p1 = state[(rb + r) * 13 + 1], p2 = state[(rb + r) * 13 + 2];
    short8 v;
#pragma unroll
    for (int j = 0; j < 8; ++j) {
      int jj = c8 * 8 + j;
      v[j] = f2bf(tanhf(p0 * tw1[jj] + p1 * tw1[256 + jj] + p2 * tw1[512 + jj] + tb1[jj]));
    }
    *(short8*)&tS[(r * 32 + swz8(c8, r)) * 8] = v;
  }

  const int wr = (wave >> 2) * 64, wc = (wave & 3) * 64;  // [128][256] tiles
  auto stageA = [&](int buf, int ks) {
    int chk = wave * 64 + lane;
    int row = chk >> 2, c = chk & 3;
    gl_lds16(h2 + (rb + row) * 512 + ks * 32 + swz4(c, row) * 8,
             aReg + buf * 8192 + wave * 1024);
  };
  auto stageB = [&](const short* W, int ldw, int buf, int ks) {
    char* dst = bReg + buf * 16384;
#pragma unroll
    for (int it = 0; it < 2; ++it) {
      int cw = it * 8 + wave;
      int chk = cw * 64 + lane;
      int row = chk >> 2, c = chk & 3;
      gl_lds16(W + (long)row * ldw + ks * 32 + swz4(c, row) * 8, dst + cw * 1024);
    }
  };
  // --- branch gemm: K=512 ---
  f32x4 acc3[4][4] = {};
  stageA(0, 0); stageB(w3T, 512, 0, 0);
#pragma unroll
  for (int ks = 0; ks < 16; ++ks) {
    __syncthreads();
    if (ks < 15) { stageA((ks & 1) ^ 1, ks + 1); stageB(w3T, 512, (ks & 1) ^ 1, ks + 1); }
    const short* Ab = (const short*)(aReg + (ks & 1) * 8192);
    const short* Bb = (const short*)(bReg + (ks & 1) * 16384);
    short8 aF[4], bF[4];
#pragma unroll
    for (int mf = 0; mf < 4; ++mf) { int row = wr + mf * 16 + fr;
      aF[mf] = *(const short8*)&Ab[row * 32 + swz4(fg, row) * 8]; }
#pragma unroll
    for (int nf = 0; nf < 4; ++nf) { int col = wc + nf * 16 + fr;
      bF[nf] = *(const short8*)&Bb[col * 32 + swz4(fg, col) * 8]; }
#pragma unroll
    for (int mf = 0; mf < 4; ++mf)
#pragma unroll
      for (int nf = 0; nf < 4; ++nf)
        acc3[mf][nf] = MFMA(aF[mf], bF[nf], acc3[mf][nf]);
  }
  __syncthreads();  // A/B reads done
  // posPad + qw1T tile into freed A region; first w4T stage
  {
    int r = tid >> 2, c = tid & 3;
    float p0 = state[(rb + r) * 13 + 0], p1 = state[(rb + r) * 13 + 1], p2 = state[(rb + r) * 13 + 2];
    short8 v;
#pragma unroll
    for (int j = 0; j < 8; ++j) {
      int k = c * 8 + j;
      v[j] = (k == 0) ? f2bf(p0) : (k == 1) ? f2bf(p1) : (k == 2) ? f2bf(p2) : (short)0;
    }
    *(short8*)&((short*)aReg)[(r * 4 + swz4(c, r)) * 8] = v;
  }
  {
    int chk = wave * 64 + lane;
    int row = chk >> 2, c = chk & 3;
    gl_lds16(qw1T + (long)row * 32 + swz4(c, row) * 8, aReg + 8192 + wave * 1024);
  }
  // --- trunk gemm: K=256, A = tS resident ---
  f32x4 accT[4][4] = {};
  stageB(w4T, 256, 0, 0);
#pragma unroll
  for (int ks = 0; ks < 8; ++ks) {
    __syncthreads();
    if (ks < 7) stageB(w4T, 256, (ks & 1) ^ 1, ks + 1);
    const short* Bb = (const short*)(bReg + (ks & 1) * 16384);
    short8 aF[4], bF[4];
#pragma unroll
    for (int mf = 0; mf < 4; ++mf) { int row = wr + mf * 16 + fr;
      aF[mf] = *(const short8*)&tS[row * 256 + swz8(ks * 4 + fg, row) * 8]; }
#pragma unroll
    for (int nf = 0; nf < 4; ++nf) { int col = wc + nf * 16 + fr;
      bF[nf] = *(const short8*)&Bb[col * 32 + swz4(fg, col) * 8]; }
#pragma unroll
    for (int mf = 0; mf < 4; ++mf)
#pragma unroll
      for (int nf = 0; nf < 4; ++nf)
        accT[mf][nf] = MFMA(aF[mf], bF[nf], accT[mf][nf]);
  }
  __syncthreads();  // t reads + B reads done
  // interaction = (branch+bb3) * tanh(trunk+tb2) -> tS (reuse)
#pragma unroll
  for (int nf = 0; nf < 4; ++nf) {
    int col = wc + nf * 16 + fr;
    float b3 = bb3[col], t2 = tb2[col];
#pragma unroll
    for (int mf = 0; mf < 4; ++mf)
#pragma unroll
      for (int i = 0; i < 4; ++i) {
        int row = wr + mf * 16 + fg * 4 + i;
        float br = acc3[mf][nf][i] + b3;
        float tr = tanhf(accT[mf][nf][i] + t2);
        tS[row * 256 + swz8(col >> 3, row) * 8 + (col & 7)] = f2bf(br * tr);
      }
  }
  // bias-net: hq = relu(posPad @ qw1T + qb1) -> bReg (reuse)
  {
    const int wr2 = (wave >> 2) * 64, wc2 = (wave & 3) * 32;
    short8 aF[4], bF[2];
#pragma unroll
    for (int mf = 0; mf < 4; ++mf) { int row = wr2 + mf * 16 + fr;
      aF[mf] = *(const short8*)&((short*)aReg)[row * 32 + swz4(fg, row) * 8]; }
#pragma unroll
    for (int nf = 0; nf < 2; ++nf) { int col = wc2 + nf * 16 + fr;
      bF[nf] = *(const short8*)&((short*)(aReg + 8192))[col * 32 + swz4(fg, col) * 8]; }
    f32x4 aq[4][2] = {};
#pragma unroll
    for (int mf = 0; mf < 4; ++mf)
#pragma unroll
      for (int nf = 0; nf < 2; ++nf)
        aq[mf][nf] = MFMA(aF[mf], bF[nf], aq[mf][nf]);
#pragma unroll
    for (int nf = 0; nf < 2; ++nf) {
      int col = wc2 + nf * 16 + fr;
      float qb = qb1[col];
#pragma unroll
      for (int mf = 0; mf < 4; ++mf)
#pragma unroll
        for (int i = 0; i < 4; ++i) {
          int row = wr2 + mf * 16 + fg * 4 + i;
          float v = fmaxf(aq[mf][nf][i] + qb, 0.f);
          ((short*)bReg)[row * 128 + swz8(col >> 3, row) * 8 + (col & 7)] = f2bf(v);
        }
    }
  }
  __syncthreads();  // inter + hq visible
  // proj: accP = inter @ pwT (K=256) + hq @ qw2T (K=128); wave owns rows wave*16..
  f32x4 accP = {0.f, 0.f, 0.f, 0.f};
  {
    int row = wave * 16 + fr;
#pragma unroll
    for (int ks = 0; ks < 8; ++ks) {
      short8 a = *(const short8*)&tS[row * 256 + swz8(ks * 4 + fg, row) * 8];
      short8 b = *(const short8*)&pwS[fr * 256 + swz8(ks * 4 + fg, fr) * 8];
      accP = MFMA(a, b, accP);
    }
#pragma unroll
    for (int ks = 0; ks < 4; ++ks) {
      short8 a = *(const short8*)&((short*)bReg)[row * 128 + swz8(ks * 4 + fg, row) * 8];
      short8 b = *(const short8*)&q2S[fr * 128 + swz8(ks * 4 + fg, fr) * 8];
      accP = MFMA(a, b, accP);
    }
  }
#pragma unroll
  for (int i = 0; i < 4; ++i)
    prS[(wave * 16 + fg * 4 + i) * 16 + fr] = accP[i];
  __syncthreads();
  // epilogue: residual + quat normalize
  if (tid < 128) {
    int r = tid;
    float rw = rwp[0];
    float ns[13];
#pragma unroll
    for (int c = 0; c < 13; ++c)
      ns[c] = state[(rb + r) * 13 + c] + rw * (prS[r * 16 + c] + pb[c] + qb2[c]);
    float qn = sqrtf(ns[3] * ns[3] + ns[4] * ns[4] + ns[5] * ns[5] + ns[6] * ns[6]) + 1e-8f;
#pragma unroll
    for (int c = 3; c < 7; ++c) ns[c] /= qn;
#pragma unroll
    for (int c = 0; c < 13; ++c) out[(rb + r) * 13 + c] = ns[c];
  }
}

extern "C" void kernel_launch(void* const* d_in, const int* in_sizes, int n_in,
                              void* d_out, int out_size, void* d_ws, size_t ws_size,
                              hipStream_t stream) {
  const float* state  = (const float*)d_in[0];
  const float* action = (const float*)d_in[1];
  const float* sensors= (const float*)d_in[2];
  const float* bw1 = (const float*)d_in[3];
  const float* bb1 = (const float*)d_in[4];
  const float* bw2 = (const float*)d_in[5];
  const float* bb2 = (const float*)d_in[6];
  const float* bw3 = (const float*)d_in[7];
  const float* bb3 = (const float*)d_in[8];
  const float* tw1 = (const float*)d_in[9];
  const float* tb1 = (const float*)d_in[10];
  const float* tw2 = (const float*)d_in[11];
  const float* tb2 = (const float*)d_in[12];
  const float* qw1 = (const float*)d_in[13];
  const float* qb1 = (const float*)d_in[14];
  const float* qw2 = (const float*)d_in[15];
  const float* qb2 = (const float*)d_in[16];
  const float* pw  = (const float*)d_in[17];
  const float* pb  = (const float*)d_in[18];
  const float* rw  = (const float*)d_in[19];
  float* out = (float*)d_out;

  char* p = (char*)d_ws;
  short* w1T = (short*)p; p += (size_t)1024 * 576 * 2;
  short* w2T = (short*)p; p += (size_t)512 * 1024 * 2;
  short* w3T = (short*)p; p += (size_t)256 * 512 * 2;
  short* w4T = (short*)p; p += (size_t)256 * 256 * 2;
  short* pwT = (short*)p; p += (size_t)16 * 256 * 2;
  short* qw1T= (short*)p; p += (size_t)128 * 32 * 2;
  short* qw2T= (short*)p; p += (size_t)16 * 128 * 2;
  const size_t fixed = (size_t)(p - (char*)d_ws);
  const size_t avail = (ws_size > fixed) ? ws_size - fixed : 0;
  long Mc = (long)(avail / 1024) & ~127L;   // h2 chunk: 512 bf16 per row
  if (Mc > B_TOTAL) Mc = B_TOTAL;
  if (Mc < 128) return;
  short* h2b = (short*)p;

  conv_wT<<<dim3(2304), dim3(256), 0, stream>>>(bw1, w1T, 544, 1024, 576);
  conv_wT<<<dim3(2048), dim3(256), 0, stream>>>(bw2, w2T, 1024, 512, 1024);
  conv_wT<<<dim3(512),  dim3(256), 0, stream>>>(bw3, w3T, 512, 256, 512);
  conv_wT<<<dim3(256),  dim3(256), 0, stream>>>(tw2, w4T, 256, 256, 256);
  conv_small<<<dim3(40), dim3(256), 0, stream>>>(pw, qw1, qw2, pwT, qw1T, qw2T);

  for (long r0 = 0; r0 < B_TOTAL; r0 += Mc) {
    long Mr = B_TOTAL - r0; if (Mr > Mc) Mr = Mc;
    k1<<<dim3(Mr / 64), dim3(512), 0, stream>>>(state + r0 * 13, action + r0 * 4, sensors,
                                                w1T, bb1, w2T, bb2, h2b);
    k2<<<dim3(Mr / 128), dim3(512), 0, stream>>>(h2b, state + r0 * 13, tw1, tb1,
                                                 w3T, bb3, w4T, tb2, pwT, qw1T, qw2T,
                                                 qb1, pb, qb2, rw, out + r0 * 13);
  }
}